// Round 5
// baseline (2229.782 us; speedup 1.0000x reference)
//
#include <hip/hip_runtime.h>
#include <hip/hip_bf16.h>
#include <math.h>

// SparseMoE: B=4, L=2048 -> T=8192 tokens, D=1024, FFN=4096, E=8, topk=2.
// Device dtype (fp32 vs bf16) is UNKNOWN -> detected at runtime (ws flag).
#define T_TOKENS 8192
#define DM 1024
#define FFNDIM 4096
#define NE 8
#define CAP 8192

typedef __attribute__((ext_vector_type(8))) __bf16 bf16x8;
typedef __attribute__((ext_vector_type(4))) float f32x4;

__device__ __forceinline__ float gelu_exact(float v) {
    return 0.5f * v * (1.0f + erff(v * 0.70710678118654752440f));
}

// 16-bit bf16 atomic add via 32-bit CAS on the containing dword.
__device__ __forceinline__ void atomic_add_bf16(__bf16* addr, float val) {
    size_t a = (size_t)addr;
    unsigned int* word = (unsigned int*)(a & ~(size_t)3);
    bool hi = (a & 2) != 0;
    unsigned int old = *((volatile unsigned int*)word), assumed;
    union { unsigned short u; __bf16 b; } cvt;
    do {
        assumed = old;
        cvt.u = hi ? (unsigned short)(assumed >> 16) : (unsigned short)(assumed & 0xffffu);
        float f = (float)cvt.b + val;
        cvt.b = (__bf16)f;
        unsigned int nw = hi ? ((assumed & 0x0000ffffu) | ((unsigned int)cvt.u << 16))
                             : ((assumed & 0xffff0000u) | (unsigned int)cvt.u);
        old = atomicCAS(word, assumed, nw);
    } while (old != assumed);
}

// ---------------- dtype detection: fp32 N(0,1) dwords are sane; bf16-pairs are not ----------------
__global__ void detect_kernel(const unsigned int* __restrict__ xraw, int* __restrict__ flag) {
    __shared__ int cnt;
    if (threadIdx.x == 0) cnt = 0;
    __syncthreads();
    int sane = 0;
    for (int i = threadIdx.x; i < 1024; i += 256) {
        union { unsigned int u; float f; } c; c.u = xraw[i];
        float a = fabsf(c.f);
        if (c.f == 0.0f || (a > 1e-8f && a < 100.0f)) sane++;   // NaN -> false -> insane
    }
    atomicAdd(&cnt, sane);
    __syncthreads();
    if (threadIdx.x == 0) *flag = (cnt > 512) ? 1 : 0;          // 1 = fp32 inputs/outputs
}

// load 32 logical elements at element offset eoff as 32 bf16 (4x uint4)
__device__ __forceinline__ void load32(const void* base, size_t eoff, bool fp32, uint4 o[4]) {
    if (!fp32) {
        const uint4* p = (const uint4*)((const __bf16*)base + eoff);
#pragma unroll
        for (int q = 0; q < 4; ++q) o[q] = p[q];
    } else {
        const float4* p = (const float4*)((const float*)base + eoff);
#pragma unroll
        for (int q = 0; q < 4; ++q) {
            float4 a = p[2 * q], b = p[2 * q + 1];
            union { __bf16 h[8]; uint4 v; } u;
            u.h[0] = (__bf16)a.x; u.h[1] = (__bf16)a.y; u.h[2] = (__bf16)a.z; u.h[3] = (__bf16)a.w;
            u.h[4] = (__bf16)b.x; u.h[5] = (__bf16)b.y; u.h[6] = (__bf16)b.z; u.h[7] = (__bf16)b.w;
            o[q] = u.v;
        }
    }
}

__device__ __forceinline__ float load_scalar(const void* base, size_t eoff, bool fp32) {
    return fp32 ? ((const float*)base)[eoff] : (float)((const __bf16*)base)[eoff];
}

// ---------------- zero d_out (dtype-sized) + counters ----------------
__global__ __launch_bounds__(256) void zero_out_kernel(void* __restrict__ out,
                                                       const int* __restrict__ flag,
                                                       int* __restrict__ counts) {
    bool fp32 = *flag != 0;
    size_t i = (size_t)blockIdx.x * 256 + threadIdx.x;   // 1,048,576 threads x 8 elements
    uint4 z = make_uint4(0u, 0u, 0u, 0u);
    if (fp32) { uint4* p = (uint4*)out + i * 2; p[0] = z; p[1] = z; }
    else      { ((uint4*)out)[i] = z; }
    if (blockIdx.x == 0 && threadIdx.x < NE) counts[threadIdx.x] = 0;
}

// ---------------- router: logits, top-2 (first-index ties), 2-way softmax ----------------
__global__ __launch_bounds__(256) void router_kernel(
        const void* __restrict__ x_, const void* __restrict__ gw_,
        const void* __restrict__ gb_, const int* __restrict__ flag,
        int* __restrict__ counts, int* __restrict__ idx_list, float* __restrict__ gate_list) {
    bool fp32 = *flag != 0;
    int wave = threadIdx.x >> 6, lane = threadIdx.x & 63;
    int tk = blockIdx.x * 4 + wave;                      // one wave per token
    float acc[NE];
#pragma unroll
    for (int e = 0; e < NE; ++e) acc[e] = 0.f;
#pragma unroll
    for (int i = 0; i < DM / 64; ++i) {
        int d = i * 64 + lane;
        float xv = load_scalar(x_, (size_t)tk * DM + d, fp32);
        float gwv[NE];
        if (fp32) {
            const float* gr = (const float*)gw_ + d * NE;
#pragma unroll
            for (int e = 0; e < NE; ++e) gwv[e] = gr[e];
        } else {
            bf16x8 g = *(const bf16x8*)((const __bf16*)gw_ + d * NE);
#pragma unroll
            for (int e = 0; e < NE; ++e) gwv[e] = (float)g[e];
        }
#pragma unroll
        for (int e = 0; e < NE; ++e) acc[e] += xv * gwv[e];
    }
#pragma unroll
    for (int e = 0; e < NE; ++e) {
#pragma unroll
        for (int m = 32; m > 0; m >>= 1) acc[e] += __shfl_xor(acc[e], m, 64);
    }
    if (lane == 0) {
        float v0 = -INFINITY, v1 = -INFINITY;
        int i0 = 0, i1 = 0;
#pragma unroll
        for (int e = 0; e < NE; ++e) {
            float l = acc[e] + load_scalar(gb_, e, fp32);
            if (l > v0) { v1 = v0; i1 = i0; v0 = l; i0 = e; }
            else if (l > v1) { v1 = l; i1 = e; }
        }
        float g0 = 1.f / (1.f + expf(v1 - v0));          // softmax over {v0,v1}, v0 = max
        float g1 = 1.f - g0;
        int p0 = atomicAdd(&counts[i0], 1);
        if (p0 < CAP) { idx_list[i0 * CAP + p0] = tk; gate_list[i0 * CAP + p0] = g0; }
        int p1 = atomicAdd(&counts[i1], 1);
        if (p1 < CAP) { idx_list[i1 * CAP + p1] = tk; gate_list[i1 * CAP + p1] = g1; }
    }
}

// ---------------- scan: pbase[e] = 128-aligned prefix; pbase[8] = padded total ----------------
__global__ void scan_kernel(const int* __restrict__ counts, int* __restrict__ pbase) {
    if (threadIdx.x == 0 && blockIdx.x == 0) {
        int s = 0;
        for (int e = 0; e < NE; ++e) {
            pbase[e] = s;
            s += (counts[e] + 127) & ~127;
        }
        pbase[NE] = s;
    }
}

__device__ __forceinline__ int find_expert(const int* pbase, int slot_tile) {
    int e = 0;
#pragma unroll
    for (int k = 0; k < NE - 1; ++k)
        if (pbase[k + 1] <= slot_tile) e = k + 1;
    return e;
}

// ---------------- gemm1: h[chunk-local slot][0..4095] = gelu(x[tok] @ w1[e] + b1[e]) ----------------
__global__ __launch_bounds__(256) void gemm1_kernel(
        const void* __restrict__ x_, const void* __restrict__ w1_,
        const void* __restrict__ b1_, const int* __restrict__ flag,
        const int* __restrict__ counts, const int* __restrict__ pbase,
        const int* __restrict__ idx_list, __bf16* __restrict__ h, int chunk_start) {
    __shared__ __bf16 Alds[128 * 72];   // [m][k], stride 72 -> conflict-free b128 reads
    __shared__ __bf16 Blds[64 * 130];   // [k][n], stride 130 -> conflict-free strided reads
    bool fp32 = *flag != 0;

    int mtl = blockIdx.x >> 5;
    int nt  = blockIdx.x & 31;
    int slot_tile = chunk_start + mtl * 128;
    if (slot_tile >= pbase[NE]) return;
    int e = find_expert(pbase, slot_tile);
    int cnt = counts[e];
    int loc_tile = slot_tile - pbase[e];
    if (loc_tile >= cnt) return;                         // pure-padding tile

    int t = threadIdx.x;
    int am = t >> 1;
    int ahalf = (t & 1) * 32;
    int localc = loc_tile + am; if (localc > cnt - 1) localc = cnt - 1;
    int tok = idx_list[e * CAP + localc];
    size_t a_eoff = (size_t)tok * DM + ahalf;
    __bf16* adst = Alds + am * 72 + ahalf;
    int bk = t >> 2;
    int bseg = (t & 3) * 32;
    size_t b_eoff = (size_t)e * (DM * FFNDIM) + (size_t)bk * FFNDIM + nt * 128 + bseg;
    unsigned int* Blds32 = (unsigned int*)Blds;
    int bdst = bk * 65 + (bseg >> 1);

    int lane = t & 63, wave = t >> 6;
    int wm = (wave >> 1) * 64, wn = (wave & 1) * 64;     // 2x2 waves of 64x64
    int l15 = lane & 15, quad = lane >> 4;

    f32x4 acc[4][4];
#pragma unroll
    for (int i = 0; i < 4; ++i)
#pragma unroll
        for (int j = 0; j < 4; ++j) acc[i][j] = f32x4{0.f, 0.f, 0.f, 0.f};

    for (int kb = 0; kb < DM; kb += 64) {
        uint4 av[4], bv[4];
        load32(x_,  a_eoff + kb, fp32, av);
        load32(w1_, b_eoff + (size_t)kb * FFNDIM, fp32, bv);
        __syncthreads();
#pragma unroll
        for (int q = 0; q < 4; ++q) {
            *(uint4*)(adst + q * 8) = av[q];
            int d = bdst + q * 4;
            Blds32[d + 0] = bv[q].x; Blds32[d + 1] = bv[q].y;
            Blds32[d + 2] = bv[q].z; Blds32[d + 3] = bv[q].w;
        }
        __syncthreads();
#pragma unroll
        for (int ks = 0; ks < 2; ++ks) {
            int ko = ks * 32 + quad * 8;
            bf16x8 af[4], bfr[4];
#pragma unroll
            for (int i = 0; i < 4; ++i)
                af[i] = *(const bf16x8*)(Alds + (wm + i * 16 + l15) * 72 + ko);
#pragma unroll
            for (int j = 0; j < 4; ++j) {
                int colb = wn + j * 16 + l15;
#pragma unroll
                for (int jj = 0; jj < 8; ++jj)
                    bfr[j][jj] = Blds[(ko + jj) * 130 + colb];
            }
#pragma unroll
            for (int i = 0; i < 4; ++i)
#pragma unroll
                for (int j = 0; j < 4; ++j)
                    acc[i][j] = __builtin_amdgcn_mfma_f32_16x16x32_bf16(
                        af[i], bfr[j], acc[i][j], 0, 0, 0);
        }
    }
    float bias[4];
#pragma unroll
    for (int j = 0; j < 4; ++j)
        bias[j] = load_scalar(b1_, (size_t)e * FFNDIM + nt * 128 + wn + j * 16 + l15, fp32);
#pragma unroll
    for (int i = 0; i < 4; ++i) {
#pragma unroll
        for (int r = 0; r < 4; ++r) {
            int rowl = wm + i * 16 + quad * 4 + r;       // C/D: col=lane&15, row=quad*4+reg
            if (loc_tile + rowl < cnt) {
                size_t hoff = (size_t)(mtl * 128 + rowl) * FFNDIM + nt * 128;
#pragma unroll
                for (int j = 0; j < 4; ++j) {
                    float v = acc[i][j][r] + bias[j];
                    h[hoff + wn + j * 16 + l15] = (__bf16)gelu_exact(v);
                }
            }
        }
    }
}

// ---------------- gemm2: out[tok] += gate * (h_slot @ w2[e] + b2[e]), K=4096 ----------------
__global__ __launch_bounds__(256) void gemm2_kernel(
        const __bf16* __restrict__ h, const void* __restrict__ w2_,
        const void* __restrict__ b2_, const int* __restrict__ flag,
        const int* __restrict__ counts, const int* __restrict__ pbase,
        const int* __restrict__ idx_list, const float* __restrict__ gate_list,
        void* __restrict__ out_, int chunk_start, int S) {
    __shared__ __bf16 Alds[128 * 72];
    __shared__ __bf16 Blds[64 * 130];
    bool fp32 = *flag != 0;

    int mtl = blockIdx.x >> 3;
    int nt  = blockIdx.x & 7;
    int slot_tile = chunk_start + mtl * 128;
    if (slot_tile >= pbase[NE]) return;
    int e = find_expert(pbase, slot_tile);
    int cnt = counts[e];
    int loc_tile = slot_tile - pbase[e];
    if (loc_tile >= cnt) return;

    int t = threadIdx.x;
    int am = t >> 1;
    int ahalf = (t & 1) * 32;
    int localc = loc_tile + am; if (localc > cnt - 1) localc = cnt - 1;
    int hrow = (pbase[e] + localc) - chunk_start;        // chunk-local h row
    if (hrow > S - 1) hrow = S - 1;                      // clamp: only padding rows hit this
    const __bf16* arow = h + (size_t)hrow * FFNDIM + ahalf;
    __bf16* adst = Alds + am * 72 + ahalf;
    int bk = t >> 2;
    int bseg = (t & 3) * 32;
    size_t b_eoff = (size_t)e * (FFNDIM * DM) + (size_t)bk * DM + nt * 128 + bseg;
    unsigned int* Blds32 = (unsigned int*)Blds;
    int bdst = bk * 65 + (bseg >> 1);

    int lane = t & 63, wave = t >> 6;
    int wm = (wave >> 1) * 64, wn = (wave & 1) * 64;
    int l15 = lane & 15, quad = lane >> 4;

    f32x4 acc[4][4];
#pragma unroll
    for (int i = 0; i < 4; ++i)
#pragma unroll
        for (int j = 0; j < 4; ++j) acc[i][j] = f32x4{0.f, 0.f, 0.f, 0.f};

    for (int kb = 0; kb < FFNDIM; kb += 64) {
        uint4 av[4], bv[4];
        const uint4* asrc = (const uint4*)(arow + kb);
#pragma unroll
        for (int q = 0; q < 4; ++q) av[q] = asrc[q];     // h is always bf16
        load32(w2_, b_eoff + (size_t)kb * DM, fp32, bv);
        __syncthreads();
#pragma unroll
        for (int q = 0; q < 4; ++q) {
            *(uint4*)(adst + q * 8) = av[q];
            int d = bdst + q * 4;
            Blds32[d + 0] = bv[q].x; Blds32[d + 1] = bv[q].y;
            Blds32[d + 2] = bv[q].z; Blds32[d + 3] = bv[q].w;
        }
        __syncthreads();
#pragma unroll
        for (int ks = 0; ks < 2; ++ks) {
            int ko = ks * 32 + quad * 8;
            bf16x8 af[4], bfr[4];
#pragma unroll
            for (int i = 0; i < 4; ++i)
                af[i] = *(const bf16x8*)(Alds + (wm + i * 16 + l15) * 72 + ko);
#pragma unroll
            for (int j = 0; j < 4; ++j) {
                int colb = wn + j * 16 + l15;
#pragma unroll
                for (int jj = 0; jj < 8; ++jj)
                    bfr[j][jj] = Blds[(ko + jj) * 130 + colb];
            }
#pragma unroll
            for (int i = 0; i < 4; ++i)
#pragma unroll
                for (int j = 0; j < 4; ++j)
                    acc[i][j] = __builtin_amdgcn_mfma_f32_16x16x32_bf16(
                        af[i], bfr[j], acc[i][j], 0, 0, 0);
        }
    }
    float b2v[4];
#pragma unroll
    for (int j = 0; j < 4; ++j)
        b2v[j] = load_scalar(b2_, (size_t)e * DM + nt * 128 + wn + j * 16 + l15, fp32);
#pragma unroll
    for (int i = 0; i < 4; ++i) {
#pragma unroll
        for (int r = 0; r < 4; ++r) {
            int rowl = wm + i * 16 + quad * 4 + r;
            int local = loc_tile + rowl;
            if (local < cnt) {
                int tok = idx_list[e * CAP + local];
                float g = gate_list[e * CAP + local];
                size_t ooff = (size_t)tok * DM + nt * 128;
#pragma unroll
                for (int j = 0; j < 4; ++j) {
                    float val = g * (acc[i][j][r] + b2v[j]);
                    size_t oidx = ooff + wn + j * 16 + l15;
                    if (fp32) atomicAdd((float*)out_ + oidx, val);
                    else      atomic_add_bf16((__bf16*)out_ + oidx, val);
                }
            }
        }
    }
}

extern "C" void kernel_launch(void* const* d_in, const int* in_sizes, int n_in,
                              void* d_out, int out_size, void* d_ws, size_t ws_size,
                              hipStream_t stream) {
    const void* x      = d_in[0];
    const void* gate_w = d_in[1];
    const void* gate_b = d_in[2];
    const void* w1     = d_in[3];
    const void* b1     = d_in[4];
    const void* w2     = d_in[5];
    const void* b2     = d_in[6];

    // ws: [flag 64B][counts 64B][pbase 64B][idx 256KiB][gate 256KiB][hbuf S*8192B]
    char* wsb = (char*)d_ws;
    int*   flag     = (int*)wsb;
    int*   counts   = (int*)(wsb + 64);
    int*   pbase    = (int*)(wsb + 128);
    int*   idx_list = (int*)(wsb + 192);
    float* gate_lst = (float*)(wsb + 192 + 262144);
    __bf16* hbuf    = (__bf16*)(wsb + 192 + 524288);
    const size_t fixed = 192 + 524288;

    int S, NCH;   // padded slot total <= 16384 + 8*127 = 17400
    if      (ws_size >= fixed + 4096ull * 8192) { S = 4096; NCH = 5;  }
    else if (ws_size >= fixed + 2048ull * 8192) { S = 2048; NCH = 9;  }
    else if (ws_size >= fixed + 1024ull * 8192) { S = 1024; NCH = 17; }
    else                                        { S = 512;  NCH = 34; }

    detect_kernel<<<1, 256, 0, stream>>>((const unsigned int*)x, flag);
    zero_out_kernel<<<4096, 256, 0, stream>>>(d_out, flag, counts);
    router_kernel<<<2048, 256, 0, stream>>>(x, gate_w, gate_b, flag, counts, idx_list, gate_lst);
    scan_kernel<<<1, 64, 0, stream>>>(counts, pbase);
    for (int c = 0; c < NCH; ++c) {
        gemm1_kernel<<<(S / 128) * 32, 256, 0, stream>>>(x, w1, b1, flag, counts, pbase,
                                                         idx_list, hbuf, c * S);
        gemm2_kernel<<<(S / 128) * 8, 256, 0, stream>>>(hbuf, w2, b2, flag, counts, pbase,
                                                        idx_list, gate_lst, d_out, c * S, S);
    }
}

// Round 6
// 2004.427 us; speedup vs baseline: 1.1124x; 1.1124x over previous
//
#include <hip/hip_runtime.h>
#include <hip/hip_bf16.h>
#include <math.h>

// SparseMoE: B=4, L=2048 -> T=8192 tokens, D=1024, FFN=4096, E=8, topk=2.
// Inputs/outputs are fp32 on device (proved in R5 by runtime dtype bisect).
// Compute: bf16 MFMA (threshold is 2% of ref max; bf16 path measured absmax 3.9e-3).
#define T_TOKENS 8192
#define DM 1024
#define FFNDIM 4096
#define NE 8
#define CAP 8192

typedef __attribute__((ext_vector_type(8))) __bf16 bf16x8;
typedef __attribute__((ext_vector_type(4))) float f32x4;

__device__ __forceinline__ float gelu_exact(float v) {
    return 0.5f * v * (1.0f + erff(v * 0.70710678118654752440f));
}

union PK8 { __bf16 h[8]; uint4 v; };

// ---------------- zero fp32 d_out + counters ----------------
__global__ __launch_bounds__(256) void zero_out_kernel(float* __restrict__ out,
                                                       int* __restrict__ counts) {
    size_t i = (size_t)blockIdx.x * 256 + threadIdx.x;   // 4096 blocks x 256 x 8 floats
    uint4 z = make_uint4(0u, 0u, 0u, 0u);
    uint4* p = (uint4*)out + i * 2;
    p[0] = z; p[1] = z;
    if (blockIdx.x == 0 && threadIdx.x < NE) counts[threadIdx.x] = 0;
}

// ---------------- router: fp32 logits, top-2 (first-index ties), 2-way softmax ----------------
__global__ __launch_bounds__(256) void router_kernel(
        const float* __restrict__ x, const float* __restrict__ gate_w,
        const float* __restrict__ gate_b, int* __restrict__ counts,
        int* __restrict__ idx_list, float* __restrict__ gate_list) {
    int wave = threadIdx.x >> 6, lane = threadIdx.x & 63;
    int tk = blockIdx.x * 4 + wave;                      // one wave per token
    const float* xr = x + (size_t)tk * DM;
    float acc[NE];
#pragma unroll
    for (int e = 0; e < NE; ++e) acc[e] = 0.f;
#pragma unroll
    for (int i = 0; i < DM / 64; ++i) {
        int d = i * 64 + lane;
        float xv = xr[d];
        f32x4 g0v = *(const f32x4*)(gate_w + d * NE);
        f32x4 g1v = *(const f32x4*)(gate_w + d * NE + 4);
#pragma unroll
        for (int e = 0; e < 4; ++e) { acc[e] += xv * g0v[e]; acc[4 + e] += xv * g1v[e]; }
    }
#pragma unroll
    for (int e = 0; e < NE; ++e) {
#pragma unroll
        for (int m = 32; m > 0; m >>= 1) acc[e] += __shfl_xor(acc[e], m, 64);
    }
    if (lane == 0) {
        float v0 = -INFINITY, v1 = -INFINITY;
        int i0 = 0, i1 = 0;
#pragma unroll
        for (int e = 0; e < NE; ++e) {
            float l = acc[e] + gate_b[e];
            if (l > v0) { v1 = v0; i1 = i0; v0 = l; i0 = e; }
            else if (l > v1) { v1 = l; i1 = e; }
        }
        float g0 = 1.f / (1.f + expf(v1 - v0));          // softmax over {v0,v1}, v0 = max
        float g1 = 1.f - g0;
        int p0 = atomicAdd(&counts[i0], 1);
        idx_list[i0 * CAP + p0] = tk;
        gate_list[i0 * CAP + p0] = g0;
        int p1 = atomicAdd(&counts[i1], 1);
        idx_list[i1 * CAP + p1] = tk;
        gate_list[i1 * CAP + p1] = g1;
    }
}

// ---------------- scan: pbase[e] = 128-aligned prefix; pbase[8] = padded total ----------------
__global__ void scan_kernel(const int* __restrict__ counts, int* __restrict__ pbase) {
    if (threadIdx.x == 0 && blockIdx.x == 0) {
        int s = 0;
        for (int e = 0; e < NE; ++e) {
            pbase[e] = s;
            s += (counts[e] + 127) & ~127;
        }
        pbase[NE] = s;
    }
}

__device__ __forceinline__ int find_expert(const int* pbase, int slot_tile) {
    int e = 0;
#pragma unroll
    for (int k = 0; k < NE - 1; ++k)
        if (pbase[k + 1] <= slot_tile) e = k + 1;
    return e;
}

// ---------------- gemm1: h[chunk-local slot][0..4095] = gelu(x[tok] @ w1[e] + b1[e]) ----------------
// grid (S/128, 32): x = m-tile within chunk, y = 128-wide n-tile over FFN. K = DM = 1024.
__global__ __launch_bounds__(256, 3) void gemm1_kernel(
        const float* __restrict__ x, const float* __restrict__ w1,
        const float* __restrict__ b1, const int* __restrict__ counts,
        const int* __restrict__ pbase, const int* __restrict__ idx_list,
        __bf16* __restrict__ h, int chunk_start) {
    __shared__ __bf16 Alds[128 * 72];   // [m][k], stride 72: b128-read friendly
    __shared__ __bf16 Btld[128 * 72];   // [n][k] TRANSPOSED: b128-read friendly

    int mtl = blockIdx.x;
    int nt  = blockIdx.y;
    int slot_tile = chunk_start + mtl * 128;
    if (slot_tile >= pbase[NE]) return;
    int e = find_expert(pbase, slot_tile);
    int cnt = counts[e];
    int loc_tile = slot_tile - pbase[e];
    if (loc_tile >= cnt) return;                         // pure-padding tile

    int t = threadIdx.x;
    // A gather staging: 2 threads/row, 32 fp32 each -> 32 bf16
    int am = t >> 1, ahalf = (t & 1) * 32;
    int localc = loc_tile + am; if (localc > cnt - 1) localc = cnt - 1;
    int tok = idx_list[e * CAP + localc];
    const float* arow = x + (size_t)tok * DM + ahalf;
    __bf16* adst = Alds + am * 72 + ahalf;
    // B transpose staging: thread covers 8k x 4n patch
    int k0 = (t & 7) * 8;
    int n0 = (t >> 3) * 4;
    const float* bbase = w1 + (size_t)e * DM * FFNDIM + (size_t)k0 * FFNDIM + nt * 128 + n0;
    __bf16* bdst = Btld + n0 * 72 + k0;

    int lane = t & 63, wave = t >> 6;
    int wm = (wave >> 1) * 64, wn = (wave & 1) * 64;     // 2x2 waves of 64x64
    int l15 = lane & 15, quad = lane >> 4;

    f32x4 acc[4][4];
#pragma unroll
    for (int i = 0; i < 4; ++i)
#pragma unroll
        for (int j = 0; j < 4; ++j) acc[i][j] = f32x4{0.f, 0.f, 0.f, 0.f};

    for (int kb = 0; kb < DM; kb += 64) {
        // global loads (fp32)
        f32x4 av[8], bv[8];
        const f32x4* ap = (const f32x4*)(arow + kb);
        const float* bp = bbase + (size_t)kb * FFNDIM;
#pragma unroll
        for (int q = 0; q < 8; ++q) av[q] = ap[q];
#pragma unroll
        for (int kk = 0; kk < 8; ++kk) bv[kk] = *(const f32x4*)(bp + (size_t)kk * FFNDIM);
        // convert to packed bf16 BEFORE the barrier (drops fp32 liveness)
        uint4 apk[4], bpk[4];
#pragma unroll
        for (int q = 0; q < 4; ++q) {
            PK8 u;
#pragma unroll
            for (int w = 0; w < 4; ++w) {
                u.h[w]     = (__bf16)av[2 * q][w];
                u.h[4 + w] = (__bf16)av[2 * q + 1][w];
            }
            apk[q] = u.v;
        }
#pragma unroll
        for (int j = 0; j < 4; ++j) {
            PK8 u;
#pragma unroll
            for (int kk = 0; kk < 8; ++kk) u.h[kk] = (__bf16)bv[kk][j];
            bpk[j] = u.v;
        }
        __syncthreads();                                 // prev iter's LDS reads done
#pragma unroll
        for (int q = 0; q < 4; ++q) *(uint4*)(adst + q * 8) = apk[q];
#pragma unroll
        for (int j = 0; j < 4; ++j) *(uint4*)(bdst + j * 72) = bpk[j];
        __syncthreads();
#pragma unroll
        for (int ks = 0; ks < 2; ++ks) {
            int ko = ks * 32 + quad * 8;
            bf16x8 af[4], bf[4];
#pragma unroll
            for (int i = 0; i < 4; ++i)
                af[i] = *(const bf16x8*)(Alds + (wm + i * 16 + l15) * 72 + ko);
#pragma unroll
            for (int j = 0; j < 4; ++j)
                bf[j] = *(const bf16x8*)(Btld + (wn + j * 16 + l15) * 72 + ko);
#pragma unroll
            for (int i = 0; i < 4; ++i)
#pragma unroll
                for (int j = 0; j < 4; ++j)
                    acc[i][j] = __builtin_amdgcn_mfma_f32_16x16x32_bf16(
                        af[i], bf[j], acc[i][j], 0, 0, 0);
        }
    }
    float bias[4];
#pragma unroll
    for (int j = 0; j < 4; ++j)
        bias[j] = b1[(size_t)e * FFNDIM + nt * 128 + wn + j * 16 + l15];
#pragma unroll
    for (int i = 0; i < 4; ++i) {
#pragma unroll
        for (int r = 0; r < 4; ++r) {
            int rowl = wm + i * 16 + quad * 4 + r;       // C/D: col=lane&15, row=quad*4+reg
            if (loc_tile + rowl < cnt) {
                size_t hoff = (size_t)(mtl * 128 + rowl) * FFNDIM + nt * 128;
#pragma unroll
                for (int j = 0; j < 4; ++j) {
                    float v = acc[i][j][r] + bias[j];
                    h[hoff + wn + j * 16 + l15] = (__bf16)gelu_exact(v);
                }
            }
        }
    }
}

// ---------------- gemm2: out[tok] += gate*(h_slot @ w2[e] slice + b2 on ksplit0) ----------------
// grid (S/128, 8, 4): x = m-tile, y = 128-wide n-tile over DM, z = K-split (1024 K each).
__global__ __launch_bounds__(256, 3) void gemm2_kernel(
        const __bf16* __restrict__ h, const float* __restrict__ w2,
        const float* __restrict__ b2, const int* __restrict__ counts,
        const int* __restrict__ pbase, const int* __restrict__ idx_list,
        const float* __restrict__ gate_list, float* __restrict__ out, int chunk_start) {
    __shared__ __bf16 Alds[128 * 72];
    __shared__ __bf16 Btld[128 * 72];

    int mtl = blockIdx.x;
    int nt  = blockIdx.y;
    int ksp = blockIdx.z;
    int slot_tile = chunk_start + mtl * 128;
    if (slot_tile >= pbase[NE]) return;
    int e = find_expert(pbase, slot_tile);
    int cnt = counts[e];
    int loc_tile = slot_tile - pbase[e];
    if (loc_tile >= cnt) return;

    int t = threadIdx.x;
    int am = t >> 1, ahalf = (t & 1) * 32;
    int localc = loc_tile + am; if (localc > cnt - 1) localc = cnt - 1;
    int hrow = (pbase[e] + localc) - chunk_start;        // chunk-local; always in [0,S)
    const __bf16* arow = h + (size_t)hrow * FFNDIM + ksp * 1024 + ahalf;
    __bf16* adst = Alds + am * 72 + ahalf;
    int k0 = (t & 7) * 8;
    int n0 = (t >> 3) * 4;
    const float* bbase = w2 + (size_t)e * FFNDIM * DM + (size_t)(ksp * 1024 + k0) * DM
                         + nt * 128 + n0;
    __bf16* bdst = Btld + n0 * 72 + k0;

    int lane = t & 63, wave = t >> 6;
    int wm = (wave >> 1) * 64, wn = (wave & 1) * 64;
    int l15 = lane & 15, quad = lane >> 4;

    f32x4 acc[4][4];
#pragma unroll
    for (int i = 0; i < 4; ++i)
#pragma unroll
        for (int j = 0; j < 4; ++j) acc[i][j] = f32x4{0.f, 0.f, 0.f, 0.f};

    for (int kb = 0; kb < 1024; kb += 64) {
        uint4 apk[4];
        f32x4 bv[8];
        const uint4* ap = (const uint4*)(arow + kb);     // h is bf16 already
        const float* bp = bbase + (size_t)kb * DM;
#pragma unroll
        for (int q = 0; q < 4; ++q) apk[q] = ap[q];
#pragma unroll
        for (int kk = 0; kk < 8; ++kk) bv[kk] = *(const f32x4*)(bp + (size_t)kk * DM);
        uint4 bpk[4];
#pragma unroll
        for (int j = 0; j < 4; ++j) {
            PK8 u;
#pragma unroll
            for (int kk = 0; kk < 8; ++kk) u.h[kk] = (__bf16)bv[kk][j];
            bpk[j] = u.v;
        }
        __syncthreads();
#pragma unroll
        for (int q = 0; q < 4; ++q) *(uint4*)(adst + q * 8) = apk[q];
#pragma unroll
        for (int j = 0; j < 4; ++j) *(uint4*)(bdst + j * 72) = bpk[j];
        __syncthreads();
#pragma unroll
        for (int ks = 0; ks < 2; ++ks) {
            int ko = ks * 32 + quad * 8;
            bf16x8 af[4], bf[4];
#pragma unroll
            for (int i = 0; i < 4; ++i)
                af[i] = *(const bf16x8*)(Alds + (wm + i * 16 + l15) * 72 + ko);
#pragma unroll
            for (int j = 0; j < 4; ++j)
                bf[j] = *(const bf16x8*)(Btld + (wn + j * 16 + l15) * 72 + ko);
#pragma unroll
            for (int i = 0; i < 4; ++i)
#pragma unroll
                for (int j = 0; j < 4; ++j)
                    acc[i][j] = __builtin_amdgcn_mfma_f32_16x16x32_bf16(
                        af[i], bf[j], acc[i][j], 0, 0, 0);
        }
    }
    float b2v[4];
#pragma unroll
    for (int j = 0; j < 4; ++j)
        b2v[j] = b2[(size_t)e * DM + nt * 128 + wn + j * 16 + l15];
#pragma unroll
    for (int i = 0; i < 4; ++i) {
#pragma unroll
        for (int r = 0; r < 4; ++r) {
            int rowl = wm + i * 16 + quad * 4 + r;
            int local = loc_tile + rowl;
            if (local < cnt) {
                int tok = idx_list[e * CAP + local];
                float g = gate_list[e * CAP + local];
                float* orow = out + (size_t)tok * DM + nt * 128;
#pragma unroll
                for (int j = 0; j < 4; ++j) {
                    float v = acc[i][j][r];
                    if (ksp == 0) v += b2v[j];           // b2 exactly once per (token,expert)
                    atomicAdd(orow + wn + j * 16 + l15, g * v);
                }
            }
        }
    }
}

extern "C" void kernel_launch(void* const* d_in, const int* in_sizes, int n_in,
                              void* d_out, int out_size, void* d_ws, size_t ws_size,
                              hipStream_t stream) {
    const float* x      = (const float*)d_in[0];
    const float* gate_w = (const float*)d_in[1];
    const float* gate_b = (const float*)d_in[2];
    const float* w1     = (const float*)d_in[3];
    const float* b1     = (const float*)d_in[4];
    const float* w2     = (const float*)d_in[5];
    const float* b2     = (const float*)d_in[6];
    float* out = (float*)d_out;

    // ws: [counts 64B][pbase 64B][idx 256KiB][gate 256KiB][hbuf S*4096*2B]
    char* wsb = (char*)d_ws;
    int*   counts   = (int*)wsb;
    int*   pbase    = (int*)(wsb + 64);
    int*   idx_list = (int*)(wsb + 128);
    float* gate_lst = (float*)(wsb + 128 + 262144);
    __bf16* hbuf    = (__bf16*)(wsb + 524416);
    const size_t fixed = 524416;

    int S, NCH;   // padded slot total <= 16384 + 8*127 = 17400
    if      (ws_size >= fixed + 4096ull * 8192) { S = 4096; NCH = 5;  }
    else if (ws_size >= fixed + 2048ull * 8192) { S = 2048; NCH = 9;  }
    else if (ws_size >= fixed + 1024ull * 8192) { S = 1024; NCH = 17; }
    else                                        { S = 512;  NCH = 34; }

    zero_out_kernel<<<4096, 256, 0, stream>>>(out, counts);
    router_kernel<<<2048, 256, 0, stream>>>(x, gate_w, gate_b, counts, idx_list, gate_lst);
    scan_kernel<<<1, 64, 0, stream>>>(counts, pbase);
    for (int c = 0; c < NCH; ++c) {
        gemm1_kernel<<<dim3(S / 128, 32), 256, 0, stream>>>(x, w1, b1, counts, pbase,
                                                            idx_list, hbuf, c * S);
        gemm2_kernel<<<dim3(S / 128, 8, 4), 256, 0, stream>>>(hbuf, w2, b2, counts, pbase,
                                                              idx_list, gate_lst, out, c * S);
    }
}